// Round 14
// baseline (102.901 us; speedup 1.0000x reference)
//
#include <hip/hip_runtime.h>
#include <hip/hip_bf16.h>

#define S1 2048
#define S2 2048
#define FEAT 768
#define NB 8
#define BK 32
#define NKT (FEAT / BK)          // 24 K-steps

typedef __attribute__((ext_vector_type(8))) short bf16x8;
typedef __attribute__((ext_vector_type(4))) float f32x4;
typedef __attribute__((ext_vector_type(16))) float f32x16;
typedef __attribute__((ext_vector_type(4))) unsigned short us4;
typedef __attribute__((address_space(1))) const unsigned int gu32;
typedef __attribute__((address_space(3))) unsigned int lu32;

static __device__ __forceinline__ unsigned short f2bf(float x) {
    unsigned u = __builtin_bit_cast(unsigned, x);
    unsigned r = u + 0x7FFFu + ((u >> 16) & 1u);   // RNE
    return (unsigned short)(r >> 16);
}

// ---------------- prepass: A=bf16(m1*wc), B=bf16(m2), Q=m1@wq, D=m2@wd ----------------
__global__ __launch_bounds__(256) void conv_kernel(
    const float* __restrict__ m1, const float* __restrict__ m2,
    const float* __restrict__ wq, const float* __restrict__ wd,
    const float* __restrict__ wc,
    unsigned short* __restrict__ A, unsigned short* __restrict__ Bm,
    float* __restrict__ Q, float* __restrict__ D) {
    int wave = threadIdx.x >> 6;
    int lane = threadIdx.x & 63;
    int g = blockIdx.x * 4 + wave;               // 0 .. 2*NB*S1-1
    bool isA = (g < NB * S1);
    int row = isA ? g : g - NB * S1;
    const float* src = isA ? m1 : m2;
    const float* w   = isA ? wq : wd;
    unsigned short* dst = (isA ? A : Bm) + (size_t)row * FEAT;
    const float4* rp = (const float4*)(src + (size_t)row * FEAT);
    const float4* wp = (const float4*)w;
    const float4* cp = (const float4*)wc;
    float acc = 0.f;
#pragma unroll
    for (int i = 0; i < 3; ++i) {
        int idx = lane + 64 * i;
        float4 a = rp[idx];
        float4 b = wp[idx];
        acc += a.x * b.x + a.y * b.y + a.z * b.z + a.w * b.w;
        float4 c;
        if (isA) c = cp[idx]; else c = float4{1.f, 1.f, 1.f, 1.f};
        us4 v = { f2bf(a.x * c.x), f2bf(a.y * c.y),
                  f2bf(a.z * c.z), f2bf(a.w * c.w) };
        *(us4*)(dst + idx * 4) = v;
    }
#pragma unroll
    for (int s = 32; s; s >>= 1) acc += __shfl_xor(acc, s, 64);
    if (lane == 0) (isA ? Q : D)[row] = acc;
}

// ---------------- 128x128 tile, BK=32, dbuf pipeline, 32x32x16 MFMA ----------------
// R14 = R13 with the MFMA shape switched 16x16x32 -> 32x32x16 (only untested
// ALU axis): same LDS bytes/FLOP, half the MFMA instructions, -17% MFMA pipe
// cyc/FLOP (m119 2495 vs m06 2075 TF), longer pipe occupancy per issue.
// Swizzle: stored slot' = slot ^ ((row>>1)&3) (pre-swizzled global source,
// R4/R13-proven). 32x32 read pattern re-derived conflict-free: rows 0-7
// start banks {0,16,4,20,8,24,12,28} -> exact 8 touches/bank.
// A/B frag: row/col = lane&31, k-half = lane>>5 (8 bf16 each).
// C layout (m74/m101): col=lane&31, row=(reg&3)+8*(reg>>2)+4*(lane>>5).
__global__ __launch_bounds__(256, 4) void gemm128w_kernel(
    const unsigned short* __restrict__ A, const unsigned short* __restrict__ Bm,
    const float* __restrict__ Q, const float* __restrict__ D,
    float* __restrict__ out) {

    __shared__ __align__(16) char ldsb[2 * 16384];   // per buf: sA 8K | sB 8K

    // XCD owns batch (bid&7); within XCD walk 8x8 quadrants (R7/R8-proven).
    const int bid = blockIdx.x;                    // 0..2047
    const int b   = bid & 7;                       // batch == XCD
    const int idx = bid >> 3;                      // 0..255
    const int qd  = idx >> 6;                      // quadrant 0..3
    const int w64 = idx & 63;
    const int tm  = ((qd >> 1) << 3) | (w64 >> 3);
    const int tn  = ((qd & 1) << 3) | (w64 & 7);

    const int tid  = threadIdx.x;
    const int lane = tid & 63;
    const int wave = tid >> 6;
    const int wm = wave >> 1, wn = wave & 1;       // 2x2 waves, 64x64 out each

    const char* Ab = (const char*)(A + ((size_t)b * S1 + (size_t)tm * 128) * FEAT);
    const char* Bb = (const char*)(Bm + ((size_t)b * S2 + (size_t)tn * 128) * FEAT);

    const int srow   = lane >> 2;                              // row 0..15 per instr
    const int scolsw = (((lane & 3) ^ ((lane >> 3) & 3)) * 16);// pre-swizzled src col

    const int l31  = lane & 31;                                // frag row/col
    const int h    = lane >> 5;                                // k-half
    const int fkb0 = ((h ^ ((lane >> 1) & 3)) * 16);           // substep 0 byte
    // substep 1 byte = fkb0 ^ 32  (slot 2+h ^ xr)

    f32x16 acc[2][2];
#pragma unroll
    for (int m = 0; m < 2; ++m)
#pragma unroll
        for (int n = 0; n < 2; ++n) acc[m][n] = (f32x16)0.f;

#define STAGE(kt) do {                                                            \
    char* _buf = ldsb + ((kt) & 1) * 16384;                                       \
    _Pragma("unroll")                                                             \
    for (int _i = 0; _i < 2; ++_i) {                                              \
        const int _j = wave * 2 + _i;          /* instr 0..7: rows _j*16+srow */  \
        __builtin_amdgcn_global_load_lds(                                         \
            (gu32*)(Ab + (size_t)(_j * 16 + srow) * (FEAT * 2)                    \
                       + (kt) * (BK * 2) + scolsw),                               \
            (lu32*)(_buf + _j * 1024), 16, 0, 0);                                 \
        __builtin_amdgcn_global_load_lds(                                         \
            (gu32*)(Bb + (size_t)(_j * 16 + srow) * (FEAT * 2)                    \
                       + (kt) * (BK * 2) + scolsw),                               \
            (lu32*)(_buf + 8192 + _j * 1024), 16, 0, 0);                          \
    }                                                                             \
} while (0)

    // prologue: stage K-tile 0, drain, barrier
    STAGE(0);
    asm volatile("s_waitcnt vmcnt(0)" ::: "memory");
    __builtin_amdgcn_s_barrier();
    asm volatile("" ::: "memory");

#pragma unroll 2
    for (int kt = 0; kt < NKT; ++kt) {
        if (kt + 1 < NKT) STAGE(kt + 1);               // into buf^1

        const char* bufc = ldsb + (kt & 1) * 16384;
#pragma unroll
        for (int s = 0; s < 2; ++s) {                  // two K=16 sub-steps
            const int fkb = fkb0 ^ (s << 5);
            bf16x8 af[2], bf[2];
#pragma unroll
            for (int n = 0; n < 2; ++n) {
                int r = wn * 64 + n * 32 + l31;
                bf[n] = *(const bf16x8*)(bufc + 8192 + r * 64 + fkb);
            }
#pragma unroll
            for (int m = 0; m < 2; ++m) {
                int r = wm * 64 + m * 32 + l31;
                af[m] = *(const bf16x8*)(bufc + r * 64 + fkb);
            }
#pragma unroll
            for (int m = 0; m < 2; ++m)
#pragma unroll
                for (int n = 0; n < 2; ++n)
                    acc[m][n] = __builtin_amdgcn_mfma_f32_32x32x16_bf16(
                        af[m], bf[n], acc[m][n], 0, 0, 0);
        }

        if (kt + 1 < NKT) {
            asm volatile("s_waitcnt vmcnt(0)" ::: "memory");  // kt+1 landed
            __builtin_amdgcn_s_barrier();
            asm volatile("" ::: "memory");
        }
    }

    // ---------------- epilogue: + Q[j] + D[k], store fp32 ----------------
    const float* Qb = Q + b * S1 + tm * 128;
    const float* Db = D + b * S2 + tn * 128;
    float dv[2];
#pragma unroll
    for (int n = 0; n < 2; ++n) dv[n] = Db[wn * 64 + n * 32 + l31];

    const size_t outbase = ((size_t)b * S1 + (size_t)tm * 128) * S2 + (size_t)tn * 128;
#pragma unroll
    for (int m = 0; m < 2; ++m) {
#pragma unroll
        for (int rg = 0; rg < 16; ++rg) {
            const int rib = (rg & 3) + 8 * (rg >> 2) + 4 * h;   // row in 32x32
            const int rl  = wm * 64 + m * 32 + rib;
            const float qv = Qb[rl];
            float* orow = out + outbase + (size_t)rl * S2 + wn * 64;
#pragma unroll
            for (int n = 0; n < 2; ++n)
                orow[n * 32 + l31] = acc[m][n][rg] + qv + dv[n];
        }
    }
#undef STAGE
}

// ================= fallback path (round-1, fp32 inputs) =================
__global__ __launch_bounds__(256) void qd_kernel(
    const float* __restrict__ m1, const float* __restrict__ m2,
    const float* __restrict__ wq, const float* __restrict__ wd,
    float* __restrict__ Q, float* __restrict__ D) {
    int wave = threadIdx.x >> 6;
    int lane = threadIdx.x & 63;
    int g = blockIdx.x * 4 + wave;
    const float* src; const float* w; float* dst; int row;
    if (g < NB * S1) { src = m1; w = wq; dst = Q; row = g; }
    else             { src = m2; w = wd; dst = D; row = g - NB * S1; }
    const float4* rp = (const float4*)(src + (size_t)row * FEAT);
    const float4* wp = (const float4*)w;
    float acc = 0.f;
#pragma unroll
    for (int i = 0; i < 3; ++i) {
        float4 a = rp[lane + 64 * i];
        float4 b = wp[lane + 64 * i];
        acc += a.x * b.x + a.y * b.y + a.z * b.z + a.w * b.w;
    }
#pragma unroll
    for (int s = 32; s; s >>= 1) acc += __shfl_xor(acc, s, 64);
    if (lane == 0) dst[row] = acc;
}

__global__ __launch_bounds__(256) void gemm_kernel(
    const float* __restrict__ m1, const float* __restrict__ m2,
    const float* __restrict__ wc,
    const float* __restrict__ Q, const float* __restrict__ D,
    float* __restrict__ out) {

    __shared__ __align__(16) char sA[128 * 64 * 2];
    __shared__ __align__(16) char sB[128 * 64 * 2];
    __shared__ float wcs[FEAT];

    const int tid = threadIdx.x;
    const int blk = blockIdx.x;
    const int b  = blk >> 8;
    const int t  = blk & 255;
    const int tm = t >> 4, tn = t & 15;

    for (int i = tid; i < FEAT; i += 256) wcs[i] = wc[i];

    const float* Abase = m1 + ((size_t)b * S1 + (size_t)tm * 128) * FEAT;
    const float* Bbase = m2 + ((size_t)b * S2 + (size_t)tn * 128) * FEAT;

    const int lane = tid & 63;
    const int wave = tid >> 6;
    const int wm = wave >> 1, wn = wave & 1;

    f32x4 acc[4][4];
#pragma unroll
    for (int m = 0; m < 4; ++m)
#pragma unroll
        for (int n = 0; n < 4; ++n) acc[m][n] = (f32x4)0.f;

    const int col4 = tid & 15;
    const int row0 = tid >> 4;

    __syncthreads();

    for (int ks = 0; ks < FEAT / 64; ++ks) {
        float4 wc4 = *(const float4*)&wcs[ks * 64 + col4 * 4];
        const float4* Ak = (const float4*)(Abase + ks * 64);
        const float4* Bk = (const float4*)(Bbase + ks * 64);

        __syncthreads();
#pragma unroll
        for (int i = 0; i < 8; ++i) {
            int r = row0 + 16 * i;
            float4 a = Ak[(size_t)r * (FEAT / 4) + col4];
            us4 av = { f2bf(a.x * wc4.x), f2bf(a.y * wc4.y),
                       f2bf(a.z * wc4.z), f2bf(a.w * wc4.w) };
            int off = r * 128 + ((col4 * 8) ^ ((r & 7) << 4));
            *(us4*)(sA + off) = av;
        }
#pragma unroll
        for (int i = 0; i < 8; ++i) {
            int r = row0 + 16 * i;
            float4 v = Bk[(size_t)r * (FEAT / 4) + col4];
            us4 bv = { f2bf(v.x), f2bf(v.y), f2bf(v.z), f2bf(v.w) };
            int off = r * 128 + ((col4 * 8) ^ ((r & 7) << 4));
            *(us4*)(sB + off) = bv;
        }
        __syncthreads();

#pragma unroll
        for (int s = 0; s < 2; ++s) {
            bf16x8 af[4], bfr[4];
#pragma unroll
            for (int m = 0; m < 4; ++m) {
                int r = wm * 64 + m * 16 + (lane & 15);
                int coff = (s * 64 + (lane >> 4) * 16) ^ ((r & 7) << 4);
                af[m] = *(const bf16x8*)(sA + r * 128 + coff);
            }
#pragma unroll
            for (int n = 0; n < 4; ++n) {
                int r = wn * 64 + n * 16 + (lane & 15);
                int coff = (s * 64 + (lane >> 4) * 16) ^ ((r & 7) << 4);
                bfr[n] = *(const bf16x8*)(sB + r * 128 + coff);
            }
#pragma unroll
            for (int m = 0; m < 4; ++m)
#pragma unroll
                for (int n = 0; n < 4; ++n)
                    acc[m][n] = __builtin_amdgcn_mfma_f32_16x16x32_bf16(
                        af[m], bfr[n], acc[m][n], 0, 0, 0);
        }
    }

    const float* Qb = Q + b * S1 + tm * 128;
    const float* Db = D + b * S2 + tn * 128;
    float dv[4];
#pragma unroll
    for (int n = 0; n < 4; ++n) dv[n] = Db[wn * 64 + n * 16 + (lane & 15)];

    const size_t outbase = ((size_t)b * S1 + (size_t)tm * 128) * S2 + (size_t)tn * 128;
#pragma unroll
    for (int m = 0; m < 4; ++m) {
#pragma unroll
        for (int i = 0; i < 4; ++i) {
            int rl = wm * 64 + m * 16 + (lane >> 4) * 4 + i;
            float qv = Qb[rl];
            float* orow = out + outbase + (size_t)rl * S2 + wn * 64;
#pragma unroll
            for (int n = 0; n < 4; ++n) {
                int cl = n * 16 + (lane & 15);
                orow[cl] = acc[m][n][i] + qv + dv[n];
            }
        }
    }
}

extern "C" void kernel_launch(void* const* d_in, const int* in_sizes, int n_in,
                              void* d_out, int out_size, void* d_ws, size_t ws_size,
                              hipStream_t stream) {
    const float* m1 = (const float*)d_in[0];
    const float* m2 = (const float*)d_in[1];
    const float* wq = (const float*)d_in[2];
    const float* wd = (const float*)d_in[3];
    const float* wc = (const float*)d_in[4];
    float* out = (float*)d_out;

    const size_t elems = (size_t)NB * S1 * FEAT;
    const size_t need = 2 * elems * sizeof(unsigned short)
                      + (size_t)(NB * S1 + NB * S2) * sizeof(float);

    if (ws_size >= need) {
        unsigned short* Abuf = (unsigned short*)d_ws;
        unsigned short* Bbuf = Abuf + elems;
        float* Q  = (float*)(Bbuf + elems);
        float* Dv = Q + NB * S1;
        conv_kernel<<<(NB * S1 + NB * S2) / 4, 256, 0, stream>>>(
            m1, m2, wq, wd, wc, Abuf, Bbuf, Q, Dv);
        gemm128w_kernel<<<NB * 16 * 16, 256, 0, stream>>>(Abuf, Bbuf, Q, Dv, out);
    } else {
        float* Q  = (float*)d_ws;
        float* Dv = Q + NB * S1;
        qd_kernel<<<(2 * NB * S1) / 4, 256, 0, stream>>>(m1, m2, wq, wd, Q, Dv);
        gemm_kernel<<<NB * 256, 256, 0, stream>>>(m1, m2, wc, Q, Dv, out);
    }
}

// Round 15
// 98.928 us; speedup vs baseline: 1.0402x; 1.0402x over previous
//
#include <hip/hip_runtime.h>
#include <hip/hip_bf16.h>

#define S1 2048
#define S2 2048
#define FEAT 768
#define NB 8
#define BK 32
#define NKT (FEAT / BK)          // 24 K-steps

typedef __attribute__((ext_vector_type(8))) short bf16x8;
typedef __attribute__((ext_vector_type(4))) float f32x4;
typedef __attribute__((ext_vector_type(4))) unsigned short us4;
typedef __attribute__((address_space(1))) const unsigned int gu32;
typedef __attribute__((address_space(3))) unsigned int lu32;

static __device__ __forceinline__ unsigned short f2bf(float x) {
    unsigned u = __builtin_bit_cast(unsigned, x);
    unsigned r = u + 0x7FFFu + ((u >> 16) & 1u);   // RNE
    return (unsigned short)(r >> 16);
}

// ---------------- prepass: A=bf16(m1*wc), B=bf16(m2), Q=m1@wq, D=m2@wd ----------------
__global__ __launch_bounds__(256) void conv_kernel(
    const float* __restrict__ m1, const float* __restrict__ m2,
    const float* __restrict__ wq, const float* __restrict__ wd,
    const float* __restrict__ wc,
    unsigned short* __restrict__ A, unsigned short* __restrict__ Bm,
    float* __restrict__ Q, float* __restrict__ D) {
    int wave = threadIdx.x >> 6;
    int lane = threadIdx.x & 63;
    int g = blockIdx.x * 4 + wave;               // 0 .. 2*NB*S1-1
    bool isA = (g < NB * S1);
    int row = isA ? g : g - NB * S1;
    const float* src = isA ? m1 : m2;
    const float* w   = isA ? wq : wd;
    unsigned short* dst = (isA ? A : Bm) + (size_t)row * FEAT;
    const float4* rp = (const float4*)(src + (size_t)row * FEAT);
    const float4* wp = (const float4*)w;
    const float4* cp = (const float4*)wc;
    float acc = 0.f;
#pragma unroll
    for (int i = 0; i < 3; ++i) {
        int idx = lane + 64 * i;
        float4 a = rp[idx];
        float4 b = wp[idx];
        acc += a.x * b.x + a.y * b.y + a.z * b.z + a.w * b.w;
        float4 c;
        if (isA) c = cp[idx]; else c = float4{1.f, 1.f, 1.f, 1.f};
        us4 v = { f2bf(a.x * c.x), f2bf(a.y * c.y),
                  f2bf(a.z * c.z), f2bf(a.w * c.w) };
        *(us4*)(dst + idx * 4) = v;
    }
#pragma unroll
    for (int s = 32; s; s >>= 1) acc += __shfl_xor(acc, s, 64);
    if (lane == 0) (isA ? Q : D)[row] = acc;
}

// ---------------- 128x128 tile, BK=32, 3-BUFFER COUNTED-PREFETCH GEMM ----------------
// R15 lever (T4, the only untested cell): NEVER drain vmcnt to 0 in the
// steady loop. NBUF=3: stage kt+2 while computing kt; end-of-iter vmcnt(4)
// leaves kt+2's 4 loads in flight and guarantees kt+1 landed. Combined with
// 3 blocks/CU (48 KB LDS) for cross-block overlap. Every prior round
// effectively drained to <=1 tile in flight at its serialization point
// (R13 NBUF=2 forced vmcnt(0); R4 counted but 1 blk/CU).
// Race-safe: buf[(kt+2)%3] last frag-read at iter kt-1, 2 barriers back.
// 64 B-row slot swizzle slot' = s ^ ((r>>1)&3) (pre-swizzled global source,
// XOR'd ds_read col): proven 0-conflict + correct in R4/R13.
__global__ __launch_bounds__(256, 3) void gemm128c_kernel(
    const unsigned short* __restrict__ A, const unsigned short* __restrict__ Bm,
    const float* __restrict__ Q, const float* __restrict__ D,
    float* __restrict__ out) {

    __shared__ __align__(16) char ldsb[3 * 16384];   // per buf: sA 8K | sB 8K

    // XCD owns batch (bid&7); within XCD walk 8x8 quadrants (R7/R8-proven).
    const int bid = blockIdx.x;                    // 0..2047
    const int b   = bid & 7;                       // batch == XCD
    const int idx = bid >> 3;                      // 0..255
    const int qd  = idx >> 6;                      // quadrant 0..3
    const int w64 = idx & 63;
    const int tm  = ((qd >> 1) << 3) | (w64 >> 3);
    const int tn  = ((qd & 1) << 3) | (w64 & 7);

    const int tid  = threadIdx.x;
    const int lane = tid & 63;
    const int wave = tid >> 6;
    const int wm = wave >> 1, wn = wave & 1;       // 2x2 waves, 64x64 out each

    const char* Ab = (const char*)(A + ((size_t)b * S1 + (size_t)tm * 128) * FEAT);
    const char* Bb = (const char*)(Bm + ((size_t)b * S2 + (size_t)tn * 128) * FEAT);

    const int srow   = lane >> 2;                              // row 0..15 per instr
    const int scolsw = (((lane & 3) ^ ((lane >> 3) & 3)) * 16);// pre-swizzled src col

    const int fr  = lane & 15;                                 // fragment row
    const int fkb = (((lane >> 4) ^ ((lane >> 1) & 3)) * 16);  // swizzled frag col

    f32x4 acc[4][4];
#pragma unroll
    for (int m = 0; m < 4; ++m)
#pragma unroll
        for (int n = 0; n < 4; ++n) acc[m][n] = (f32x4)0.f;

#define STAGE(kt) do {                                                            \
    char* _buf = ldsb + ((kt) % 3) * 16384;                                       \
    _Pragma("unroll")                                                             \
    for (int _i = 0; _i < 2; ++_i) {                                              \
        const int _j = wave * 2 + _i;          /* instr 0..7: rows _j*16+srow */  \
        __builtin_amdgcn_global_load_lds(                                         \
            (gu32*)(Ab + (size_t)(_j * 16 + srow) * (FEAT * 2)                    \
                       + (kt) * (BK * 2) + scolsw),                               \
            (lu32*)(_buf + _j * 1024), 16, 0, 0);                                 \
        __builtin_amdgcn_global_load_lds(                                         \
            (gu32*)(Bb + (size_t)(_j * 16 + srow) * (FEAT * 2)                    \
                       + (kt) * (BK * 2) + scolsw),                               \
            (lu32*)(_buf + 8192 + _j * 1024), 16, 0, 0);                          \
    }                                                                             \
} while (0)

    // prologue: stage tiles 0,1; guarantee tile 0 landed (tile 1 in flight)
    STAGE(0);
    STAGE(1);
    asm volatile("s_waitcnt vmcnt(4)" ::: "memory");
    __builtin_amdgcn_s_barrier();
    asm volatile("" ::: "memory");

#pragma unroll 3
    for (int kt = 0; kt < NKT; ++kt) {
        if (kt + 2 < NKT) STAGE(kt + 2);               // into buf[(kt+2)%3]

        const char* bufc = ldsb + (kt % 3) * 16384;
        bf16x8 af[4], bfr[4];
#pragma unroll
        for (int n = 0; n < 4; ++n) {
            int r = wn * 64 + n * 16 + fr;
            bfr[n] = *(const bf16x8*)(bufc + 8192 + r * 64 + fkb);
        }
#pragma unroll
        for (int m = 0; m < 4; ++m) {
            int r = wm * 64 + m * 16 + fr;
            af[m] = *(const bf16x8*)(bufc + r * 64 + fkb);
        }
#pragma unroll
        for (int m = 0; m < 4; ++m)
#pragma unroll
            for (int n = 0; n < 4; ++n)
                acc[m][n] = __builtin_amdgcn_mfma_f32_16x16x32_bf16(
                    af[m], bfr[n], acc[m][n], 0, 0, 0);

        if (kt + 1 < NKT) {
            // counted: kt+1 landed, kt+2's 4 loads stay in flight
            if (kt + 2 < NKT) asm volatile("s_waitcnt vmcnt(4)" ::: "memory");
            else              asm volatile("s_waitcnt vmcnt(0)" ::: "memory");
            __builtin_amdgcn_s_barrier();
            asm volatile("" ::: "memory");
        }
    }

    // ---------------- epilogue: + Q[j] + D[k], store fp32 ----------------
    const int kg = lane >> 4;
    const float* Qb = Q + b * S1 + tm * 128;
    const float* Db = D + b * S2 + tn * 128;
    float dv[4];
#pragma unroll
    for (int n = 0; n < 4; ++n) dv[n] = Db[wn * 64 + n * 16 + fr];

    const size_t outbase = ((size_t)b * S1 + (size_t)tm * 128) * S2 + (size_t)tn * 128;
#pragma unroll
    for (int m = 0; m < 4; ++m) {
#pragma unroll
        for (int i = 0; i < 4; ++i) {
            int rl = wm * 64 + m * 16 + kg * 4 + i;
            float qv = Qb[rl];
            float* orow = out + outbase + (size_t)rl * S2 + wn * 64;
#pragma unroll
            for (int n = 0; n < 4; ++n)
                orow[n * 16 + fr] = acc[m][n][i] + qv + dv[n];
        }
    }
#undef STAGE
}

// ================= fallback path (round-1, fp32 inputs) =================
__global__ __launch_bounds__(256) void qd_kernel(
    const float* __restrict__ m1, const float* __restrict__ m2,
    const float* __restrict__ wq, const float* __restrict__ wd,
    float* __restrict__ Q, float* __restrict__ D) {
    int wave = threadIdx.x >> 6;
    int lane = threadIdx.x & 63;
    int g = blockIdx.x * 4 + wave;
    const float* src; const float* w; float* dst; int row;
    if (g < NB * S1) { src = m1; w = wq; dst = Q; row = g; }
    else             { src = m2; w = wd; dst = D; row = g - NB * S1; }
    const float4* rp = (const float4*)(src + (size_t)row * FEAT);
    const float4* wp = (const float4*)w;
    float acc = 0.f;
#pragma unroll
    for (int i = 0; i < 3; ++i) {
        float4 a = rp[lane + 64 * i];
        float4 b = wp[lane + 64 * i];
        acc += a.x * b.x + a.y * b.y + a.z * b.z + a.w * b.w;
    }
#pragma unroll
    for (int s = 32; s; s >>= 1) acc += __shfl_xor(acc, s, 64);
    if (lane == 0) dst[row] = acc;
}

__global__ __launch_bounds__(256) void gemm_kernel(
    const float* __restrict__ m1, const float* __restrict__ m2,
    const float* __restrict__ wc,
    const float* __restrict__ Q, const float* __restrict__ D,
    float* __restrict__ out) {

    __shared__ __align__(16) char sA[128 * 64 * 2];
    __shared__ __align__(16) char sB[128 * 64 * 2];
    __shared__ float wcs[FEAT];

    const int tid = threadIdx.x;
    const int blk = blockIdx.x;
    const int b  = blk >> 8;
    const int t  = blk & 255;
    const int tm = t >> 4, tn = t & 15;

    for (int i = tid; i < FEAT; i += 256) wcs[i] = wc[i];

    const float* Abase = m1 + ((size_t)b * S1 + (size_t)tm * 128) * FEAT;
    const float* Bbase = m2 + ((size_t)b * S2 + (size_t)tn * 128) * FEAT;

    const int lane = tid & 63;
    const int wave = tid >> 6;
    const int wm = wave >> 1, wn = wave & 1;

    f32x4 acc[4][4];
#pragma unroll
    for (int m = 0; m < 4; ++m)
#pragma unroll
        for (int n = 0; n < 4; ++n) acc[m][n] = (f32x4)0.f;

    const int col4 = tid & 15;
    const int row0 = tid >> 4;

    __syncthreads();

    for (int ks = 0; ks < FEAT / 64; ++ks) {
        float4 wc4 = *(const float4*)&wcs[ks * 64 + col4 * 4];
        const float4* Ak = (const float4*)(Abase + ks * 64);
        const float4* Bk = (const float4*)(Bbase + ks * 64);

        __syncthreads();
#pragma unroll
        for (int i = 0; i < 8; ++i) {
            int r = row0 + 16 * i;
            float4 a = Ak[(size_t)r * (FEAT / 4) + col4];
            us4 av = { f2bf(a.x * wc4.x), f2bf(a.y * wc4.y),
                       f2bf(a.z * wc4.z), f2bf(a.w * wc4.w) };
            int off = r * 128 + ((col4 * 8) ^ ((r & 7) << 4));
            *(us4*)(sA + off) = av;
        }
#pragma unroll
        for (int i = 0; i < 8; ++i) {
            int r = row0 + 16 * i;
            float4 v = Bk[(size_t)r * (FEAT / 4) + col4];
            us4 bv = { f2bf(v.x), f2bf(v.y), f2bf(v.z), f2bf(v.w) };
            int off = r * 128 + ((col4 * 8) ^ ((r & 7) << 4));
            *(us4*)(sB + off) = bv;
        }
        __syncthreads();

#pragma unroll
        for (int s = 0; s < 2; ++s) {
            bf16x8 af[4], bfr[4];
#pragma unroll
            for (int m = 0; m < 4; ++m) {
                int r = wm * 64 + m * 16 + (lane & 15);
                int coff = (s * 64 + (lane >> 4) * 16) ^ ((r & 7) << 4);
                af[m] = *(const bf16x8*)(sA + r * 128 + coff);
            }
#pragma unroll
            for (int n = 0; n < 4; ++n) {
                int r = wn * 64 + n * 16 + (lane & 15);
                int coff = (s * 64 + (lane >> 4) * 16) ^ ((r & 7) << 4);
                bfr[n] = *(const bf16x8*)(sB + r * 128 + coff);
            }
#pragma unroll
            for (int m = 0; m < 4; ++m)
#pragma unroll
                for (int n = 0; n < 4; ++n)
                    acc[m][n] = __builtin_amdgcn_mfma_f32_16x16x32_bf16(
                        af[m], bfr[n], acc[m][n], 0, 0, 0);
        }
    }

    const float* Qb = Q + b * S1 + tm * 128;
    const float* Db = D + b * S2 + tn * 128;
    float dv[4];
#pragma unroll
    for (int n = 0; n < 4; ++n) dv[n] = Db[wn * 64 + n * 16 + (lane & 15)];

    const size_t outbase = ((size_t)b * S1 + (size_t)tm * 128) * S2 + (size_t)tn * 128;
#pragma unroll
    for (int m = 0; m < 4; ++m) {
#pragma unroll
        for (int i = 0; i < 4; ++i) {
            int rl = wm * 64 + m * 16 + (lane >> 4) * 4 + i;
            float qv = Qb[rl];
            float* orow = out + outbase + (size_t)rl * S2 + wn * 64;
#pragma unroll
            for (int n = 0; n < 4; ++n) {
                int cl = n * 16 + (lane & 15);
                orow[cl] = acc[m][n][i] + qv + dv[n];
            }
        }
    }
}

extern "C" void kernel_launch(void* const* d_in, const int* in_sizes, int n_in,
                              void* d_out, int out_size, void* d_ws, size_t ws_size,
                              hipStream_t stream) {
    const float* m1 = (const float*)d_in[0];
    const float* m2 = (const float*)d_in[1];
    const float* wq = (const float*)d_in[2];
    const float* wd = (const float*)d_in[3];
    const float* wc = (const float*)d_in[4];
    float* out = (float*)d_out;

    const size_t elems = (size_t)NB * S1 * FEAT;
    const size_t need = 2 * elems * sizeof(unsigned short)
                      + (size_t)(NB * S1 + NB * S2) * sizeof(float);

    if (ws_size >= need) {
        unsigned short* Abuf = (unsigned short*)d_ws;
        unsigned short* Bbuf = Abuf + elems;
        float* Q  = (float*)(Bbuf + elems);
        float* Dv = Q + NB * S1;
        conv_kernel<<<(NB * S1 + NB * S2) / 4, 256, 0, stream>>>(
            m1, m2, wq, wd, wc, Abuf, Bbuf, Q, Dv);
        gemm128c_kernel<<<NB * 16 * 16, 256, 0, stream>>>(Abuf, Bbuf, Q, Dv, out);
    } else {
        float* Q  = (float*)d_ws;
        float* Dv = Q + NB * S1;
        qd_kernel<<<(2 * NB * S1) / 4, 256, 0, stream>>>(m1, m2, wq, wd, Q, Dv);
        gemm_kernel<<<NB * 256, 256, 0, stream>>>(m1, m2, wc, Q, Dv, out);
    }
}